// Round 3
// baseline (291.209 us; speedup 1.0000x reference)
//
#include <hip/hip_runtime.h>
#include <hip/hip_bf16.h>

// Problem constants (B=4, Y=64, X=64, C=256, H=8, F=32, RY=RX=3 -> 7x7=49 window)
// ALL inputs and the output are FLOAT32 (per the reference; the test label's
// "bf16" string is hard-coded in the generated f-string and means nothing).
static constexpr int NPOS = 4 * 64 * 64;   // 16384 spatial positions
static constexpr int CD   = 256;           // channels = H*F

__device__ __forceinline__ float bflo(unsigned int u) { return __uint_as_float(u << 16); }
__device__ __forceinline__ float bfhi(unsigned int u) { return __uint_as_float(u & 0xffff0000u); }

__device__ __forceinline__ unsigned int packbf2(float lo, float hi) {
    union { __hip_bfloat162 h; unsigned int u; } cv;
    cv.h.x = __float2bfloat16(lo);
    cv.h.y = __float2bfloat16(hi);
    return cv.u;
}

// ---------------------------------------------------------------------------
// Kernel 1: QKV projection. grid=(NPOS/16, 3), block=256.
// Block: 16 rows x 256 cols of one matrix (blockIdx.y: 0=Q,1=K,2=V).
// Thread t: cols {2*(t&127), +1}, rows (t>>7)*8 .. +7. x staged f32 in LDS.
// Q gets pos_emb[qidx] added, packed bf16 -> Qo. K stored f32 (in d_out
// scratch). V packed bf16.
// ---------------------------------------------------------------------------
__global__ __launch_bounds__(256) void qkv_kernel(
    const float* __restrict__ xin,
    const float* __restrict__ Wq,
    const float* __restrict__ Wk,
    const float* __restrict__ Wv,
    const float* __restrict__ pe,
    unsigned int* __restrict__ Qo,     // bf16x2 packed, [NPOS][128]
    float* __restrict__ Ko,            // f32 [NPOS][256]  (= d_out scratch)
    unsigned int* __restrict__ Vo)     // bf16x2 packed, [NPOS][128]
{
    __shared__ float xs[16 * 256];
    const int t = threadIdx.x;
    const int rowbase = blockIdx.x * 16;
    const int mat = blockIdx.y;

    // stage 16 rows of x (16*256 f32 = 16KB): 1024 float4, 4 per thread
    const float4* xsrc = (const float4*)(xin + (size_t)rowbase * CD);
    float4* xs4 = (float4*)xs;
#pragma unroll
    for (int i = 0; i < 4; ++i)
        xs4[i * 256 + t] = xsrc[i * 256 + t];
    __syncthreads();

    const float* W = (mat == 0) ? Wq : (mat == 1) ? Wk : Wv;
    const float2* Wp = (const float2*)W;   // rows of 256 f32 = 128 float2
    const int cp = t & 127;
    const int c0 = cp * 2;
    const int rh = (t >> 7) * 8;

    float acc0[8], acc1[8];
#pragma unroll
    for (int r = 0; r < 8; ++r) { acc0[r] = 0.f; acc1[r] = 0.f; }

#pragma unroll 4
    for (int k = 0; k < 256; ++k) {
        float2 w = Wp[k * 128 + cp];
        const float* xr = &xs[rh * 256 + k];
#pragma unroll
        for (int r = 0; r < 8; ++r) {
            float a = xr[r * 256];        // wave-uniform address -> LDS broadcast
            acc0[r] = fmaf(a, w.x, acc0[r]);
            acc1[r] = fmaf(a, w.y, acc1[r]);
        }
    }

    if (mat == 0) {
        const float2* peu = (const float2*)pe;  // [49][128] float2
#pragma unroll
        for (int r = 0; r < 8; ++r) {
            int row = rowbase + rh + r;
            int yy = (row >> 6) & 63, xx = row & 63;
            int cy = min(max(yy, 3), 60), cx = min(max(xx, 3), 60);
            int qidx = (yy - cy + 3) * 7 + (xx - cx + 3);
            float2 p = peu[qidx * 128 + cp];
            Qo[(size_t)row * 128 + cp] = packbf2(acc0[r] + p.x, acc1[r] + p.y);
        }
    } else if (mat == 1) {
#pragma unroll
        for (int r = 0; r < 8; ++r) {
            int row = rowbase + rh + r;
            float2 o; o.x = acc0[r]; o.y = acc1[r];
            *(float2*)(Ko + (size_t)row * CD + c0) = o;
        }
    } else {
#pragma unroll
        for (int r = 0; r < 8; ++r) {
            int row = rowbase + rh + r;
            Vo[(size_t)row * 128 + cp] = packbf2(acc0[r], acc1[r]);
        }
    }
}

// ---------------------------------------------------------------------------
// Kernel 2: local attention. grid=NPOS/4, block=256 (4 waves, 1 wave = 1 pos).
// Lane -> channels c=4*lane..+3 (head = lane>>3); 8-lane shfl_xor reduce.
// Online softmax over 49 slots, f32 accumulation.
// Q (bf16) is read per-lane then the SAME address is overwritten with the
// bf16 attention output at the end (in-place reuse; no cross-lane hazard).
// K is f32 (lives in d_out; read-only here).
// ---------------------------------------------------------------------------
__global__ __launch_bounds__(256) void attn_kernel(
    unsigned int* QA,                         // bf16x2 [NPOS][128], in+out
    const float* __restrict__ Kw,             // f32 [NPOS][256]
    const unsigned int* __restrict__ Vw,      // bf16x2 [NPOS][128]
    const float* __restrict__ pe)             // f32 [49][256]
{
    const int lane = threadIdx.x & 63;
    const int pos = blockIdx.x * 4 + (threadIdx.x >> 6);
    const int xx = pos & 63;
    const int yy = (pos >> 6) & 63;
    const int bb = pos >> 12;
    const int cy = min(max(yy, 3), 60);
    const int cx = min(max(xx, 3), 60);
    const int c = lane * 4;
    const int c2 = lane * 2;                  // packed-uint index

    // own Q fragment (4 channels)
    const unsigned int* qp = QA + (size_t)pos * 128 + c2;
    unsigned int q01 = qp[0], q23 = qp[1];
    const float qx = bflo(q01), qy = bfhi(q01), qz = bflo(q23), qw = bfhi(q23);

    float m = -1e9f, l = 0.f;
    float a0 = 0.f, a1 = 0.f, a2 = 0.f, a3 = 0.f;
    const int center = (bb << 12) + (cy << 6) + cx;

    for (int sy = 0; sy < 7; ++sy) {
        const int nbase = center + ((sy - 3) << 6) - 3;
#pragma unroll
        for (int sx = 0; sx < 7; ++sx) {
            const int np = nbase + sx;
            const int s  = sy * 7 + sx;
            const float4 k4 = *(const float4*)(Kw + (size_t)np * CD + c);
            const float4 p4 = *(const float4*)(pe + (size_t)s * CD + c);
            float part = fmaf(qx, k4.x + p4.x,
                         fmaf(qy, k4.y + p4.y,
                         fmaf(qz, k4.z + p4.z,
                              qw * (k4.w + p4.w))));
            part += __shfl_xor(part, 1);
            part += __shfl_xor(part, 2);
            part += __shfl_xor(part, 4);
            float sc = part * 0.17677669529663687f;   // 1/sqrt(32)
            float nm = fmaxf(m, sc);
            float alpha = __expf(m - nm);
            float p = __expf(sc - nm);
            l = l * alpha + p;
            const unsigned int* vp = Vw + (size_t)np * 128 + c2;
            const unsigned int v01 = vp[0], v23 = vp[1];
            a0 = fmaf(a0, alpha, p * bflo(v01));
            a1 = fmaf(a1, alpha, p * bfhi(v01));
            a2 = fmaf(a2, alpha, p * bflo(v23));
            a3 = fmaf(a3, alpha, p * bfhi(v23));
            m = nm;
        }
    }
    const float inv = 1.f / (l + 1e-8f);
    unsigned int* op = QA + (size_t)pos * 128 + c2;
    op[0] = packbf2(a0 * inv, a1 * inv);
    op[1] = packbf2(a2 * inv, a3 * inv);
}

// ---------------------------------------------------------------------------
// Kernel 3: output projection A(bf16) @ Wo(f32) -> out f32 (overwrites the
// K scratch in d_out; attn has already finished reading K — stream order).
// ---------------------------------------------------------------------------
__global__ __launch_bounds__(256) void oproj_kernel(
    const unsigned int* __restrict__ A,   // bf16x2 [NPOS][128]
    const float* __restrict__ Wo,
    float* __restrict__ out)
{
    __shared__ float xs[16 * 256];
    const int t = threadIdx.x;
    const int rowbase = blockIdx.x * 16;

    // stage 16 rows of A: 4096 bf16 = 512 uint4; 2 per thread, unpack to f32
    const uint4* asrc = (const uint4*)(A + (size_t)rowbase * 128);
#pragma unroll
    for (int i = 0; i < 2; ++i) {
        uint4 v = asrc[i * 256 + t];
        int f0 = (i * 256 + t) * 8;
        xs[f0 + 0] = bflo(v.x); xs[f0 + 1] = bfhi(v.x);
        xs[f0 + 2] = bflo(v.y); xs[f0 + 3] = bfhi(v.y);
        xs[f0 + 4] = bflo(v.z); xs[f0 + 5] = bfhi(v.z);
        xs[f0 + 6] = bflo(v.w); xs[f0 + 7] = bfhi(v.w);
    }
    __syncthreads();

    const float2* Wp = (const float2*)Wo;
    const int cp = t & 127;
    const int c0 = cp * 2;
    const int rh = (t >> 7) * 8;

    float acc0[8], acc1[8];
#pragma unroll
    for (int r = 0; r < 8; ++r) { acc0[r] = 0.f; acc1[r] = 0.f; }

#pragma unroll 4
    for (int k = 0; k < 256; ++k) {
        float2 w = Wp[k * 128 + cp];
        const float* xr = &xs[rh * 256 + k];
#pragma unroll
        for (int r = 0; r < 8; ++r) {
            float a = xr[r * 256];
            acc0[r] = fmaf(a, w.x, acc0[r]);
            acc1[r] = fmaf(a, w.y, acc1[r]);
        }
    }

#pragma unroll
    for (int r = 0; r < 8; ++r) {
        int row = rowbase + rh + r;
        float2 o; o.x = acc0[r]; o.y = acc1[r];
        *(float2*)(out + (size_t)row * CD + c0) = o;
    }
}

// ---------------------------------------------------------------------------
// Memory plan (ws need: 16 MB total; d_out doubles as 16 MB K-scratch):
//   ws[0,  8MB):  Q bf16 (pos_emb added) -> overwritten in place by A bf16
//   ws[8, 16MB):  V bf16
//   d_out[0,16MB): K f32 scratch, then final out f32 (oproj overwrites all)
// ---------------------------------------------------------------------------
extern "C" void kernel_launch(void* const* d_in, const int* in_sizes, int n_in,
                              void* d_out, int out_size, void* d_ws, size_t ws_size,
                              hipStream_t stream)
{
    const float* x  = (const float*)d_in[0];
    const float* Wq = (const float*)d_in[1];
    const float* Wk = (const float*)d_in[2];
    const float* Wv = (const float*)d_in[3];
    const float* Wo = (const float*)d_in[4];
    const float* pe = (const float*)d_in[5];
    float* out = (float*)d_out;

    char* ws = (char*)d_ws;
    unsigned int* QAw = (unsigned int*)ws;                    // 8 MB bf16 Q->A
    unsigned int* Vw  = (unsigned int*)(ws + (8u << 20));     // 8 MB bf16 V
    float* Kw = out;                                          // 16 MB f32 scratch

    dim3 g1(NPOS / 16, 3);
    qkv_kernel<<<g1, 256, 0, stream>>>(x, Wq, Wk, Wv, pe, QAw, Kw, Vw);
    attn_kernel<<<NPOS / 4, 256, 0, stream>>>(QAw, Kw, Vw, pe);
    oproj_kernel<<<NPOS / 16, 256, 0, stream>>>(QAw, Wo, out);
}

// Round 4
// 173.060 us; speedup vs baseline: 1.6827x; 1.6827x over previous
//
#include <hip/hip_runtime.h>
#include <hip/hip_bf16.h>

// B=4, Y=64, X=64, C=256, H=8, F=32, 7x7 window (S=49). All I/O is FLOAT32.
static constexpr int NPOS = 4 * 64 * 64;   // 16384 rows
static constexpr int CD   = 256;

typedef __attribute__((ext_vector_type(8))) short bf16x8;   // MFMA A/B frag (4 VGPR)
typedef __attribute__((ext_vector_type(4))) float f32x4;    // MFMA C/D frag

__device__ __forceinline__ float bflo(unsigned int u) { return __uint_as_float(u << 16); }
__device__ __forceinline__ float bfhi(unsigned int u) { return __uint_as_float(u & 0xffff0000u); }

__device__ __forceinline__ unsigned int packbf2(float lo, float hi) {
    union { __hip_bfloat162 h; unsigned int u; } cv;
    cv.h.x = __float2bfloat16(lo);
    cv.h.y = __float2bfloat16(hi);
    return cv.u;
}

// ---------------------------------------------------------------------------
// Convert kernel: pack Wq|Wk|Wv (6 col-tiles of 128) and Wo (2 col-tiles) into
// MFMA b-fragment order, bf16:
//   slot = (T*8 + kstep)*8 + ng   (ng = 16-col group within the 128-col tile)
//   lane L holds W[k = kstep*32 + (L>>4)*8 + j][n = T*128 + ng*16 + (L&15)]
// so a wave's b-frag is ONE coalesced 16B/lane load: Wfrag + (slot*64+L)*8.
// 32768 threads = 128 blocks x 256.
// ---------------------------------------------------------------------------
__global__ __launch_bounds__(256) void convert_kernel(
    const float* __restrict__ Wq, const float* __restrict__ Wk,
    const float* __restrict__ Wv, const float* __restrict__ Wo,
    __hip_bfloat16* __restrict__ Wfrag,    // 6*8*8*64*8 = 196608 elems (384 KB)
    __hip_bfloat16* __restrict__ Wofrag)   // 2*8*8*64*8 =  65536 elems (128 KB)
{
    int t = blockIdx.x * 256 + threadIdx.x;
    if (t < 24576) {
        int L = t & 63, ng = (t >> 6) & 7, s = (t >> 9) & 7, T = t >> 12;
        int mat = T >> 1;
        const float* src = (mat == 0) ? Wq : (mat == 1) ? Wk : Wv;
        int ncol  = (T & 1) * 128 + ng * 16 + (L & 15);
        int kbase = s * 32 + (L >> 4) * 8;
        __hip_bfloat16* dst = Wfrag + ((size_t)((T * 8 + s) * 8 + ng) * 64 + L) * 8;
#pragma unroll
        for (int j = 0; j < 8; ++j)
            dst[j] = __float2bfloat16(src[(kbase + j) * 256 + ncol]);
    } else {
        int u = t - 24576;
        int L = u & 63, ng = (u >> 6) & 7, s = (u >> 9) & 7, T = (u >> 12) & 1;
        int ncol  = T * 128 + ng * 16 + (L & 15);
        int kbase = s * 32 + (L >> 4) * 8;
        __hip_bfloat16* dst = Wofrag + ((size_t)((T * 8 + s) * 8 + ng) * 64 + L) * 8;
#pragma unroll
        for (int j = 0; j < 8; ++j)
            dst[j] = __float2bfloat16(Wo[(kbase + j) * 256 + ncol]);
    }
}

// ---------------------------------------------------------------------------
// Kernel 1: fused QKV GEMM via MFMA. C[16384 x 768] = x[16384 x 256] @ Wcat.
// grid = (128 row-blocks, 6 col-tiles T). Block: 128x128 tile, 4 waves, each
// wave 64x64 = 4x4 frags of 16x16x32. A (x, f32) is converted to bf16 in
// registers and staged to LDS; B frags come straight from L2-hot Wfrag.
// Epilogue: T<2 -> Q (+pos_emb, bf16 to QA); T 2,3 -> K bf16; T 4,5 -> V bf16.
// ---------------------------------------------------------------------------
__global__ __launch_bounds__(256) void qkv_mfma(
    const float* __restrict__ x,
    const __hip_bfloat16* __restrict__ Wfrag,
    const float* __restrict__ pe,
    __hip_bfloat16* __restrict__ QA,
    __hip_bfloat16* __restrict__ Kd,
    __hip_bfloat16* __restrict__ Vd)
{
    __shared__ __align__(16) short As[128 * 32];   // 8 KB A-tile (bf16)
    const int t = threadIdx.x;
    const int rowbase = blockIdx.x * 128;
    const int T = blockIdx.y;
    const int L = t & 63;
    const int wave = t >> 6;
    const int wm = wave & 1, wn = wave >> 1;
    const int quad = L >> 4, lrow = L & 15;

    f32x4 zero = {0.f, 0.f, 0.f, 0.f};
    f32x4 acc[4][4];
#pragma unroll
    for (int i = 0; i < 4; ++i)
#pragma unroll
        for (int j = 0; j < 4; ++j) acc[i][j] = zero;

    const int r_st = t >> 1;               // staging: 2 threads per row
    const int kh   = (t & 1) * 16;         // 16 k-values each
    const float* xsrc = x + (size_t)(rowbase + r_st) * CD + kh;
    uint4* As4 = (uint4*)As;
    const int as4_idx = r_st * 4 + (t & 1) * 2;

    for (int s = 0; s < 8; ++s) {          // K = 256, BK = 32
        if (s) __syncthreads();
        const float4* xp = (const float4*)(xsrc + s * 32);
        float4 f0 = xp[0], f1 = xp[1], f2 = xp[2], f3 = xp[3];
        uint4 u0, u1;
        u0.x = packbf2(f0.x, f0.y); u0.y = packbf2(f0.z, f0.w);
        u0.z = packbf2(f1.x, f1.y); u0.w = packbf2(f1.z, f1.w);
        u1.x = packbf2(f2.x, f2.y); u1.y = packbf2(f2.z, f2.w);
        u1.z = packbf2(f3.x, f3.y); u1.w = packbf2(f3.z, f3.w);
        As4[as4_idx] = u0; As4[as4_idx + 1] = u1;
        __syncthreads();

        bf16x8 bf[4];
#pragma unroll
        for (int j = 0; j < 4; ++j)
            bf[j] = *(const bf16x8*)(Wfrag +
                     ((size_t)((T * 8 + s) * 8 + wn * 4 + j) * 64 + L) * 8);
#pragma unroll
        for (int i = 0; i < 4; ++i) {
            bf16x8 af = *(const bf16x8*)(As + (wm * 64 + i * 16 + lrow) * 32 + quad * 8);
#pragma unroll
            for (int j = 0; j < 4; ++j)
                acc[i][j] = __builtin_amdgcn_mfma_f32_16x16x32_bf16(af, bf[j], acc[i][j], 0, 0, 0);
        }
    }

    // Epilogue. C/D layout: row = quad*4 + reg, col = lane&15 (per frag).
#pragma unroll
    for (int i = 0; i < 4; ++i) {
#pragma unroll
        for (int r = 0; r < 4; ++r) {
            int row = rowbase + wm * 64 + i * 16 + quad * 4 + r;
            if (T < 2) {
                int yy = (row >> 6) & 63, xx = row & 63;
                int cy = min(max(yy, 3), 60), cx = min(max(xx, 3), 60);
                int qidx = (yy - cy + 3) * 7 + (xx - cx + 3);
#pragma unroll
                for (int j = 0; j < 4; ++j) {
                    int c = T * 128 + wn * 64 + j * 16 + lrow;
                    QA[(size_t)row * CD + c] =
                        __float2bfloat16(acc[i][j][r] + pe[qidx * 256 + c]);
                }
            } else {
                __hip_bfloat16* O = (T < 4) ? Kd : Vd;
#pragma unroll
                for (int j = 0; j < 4; ++j) {
                    int c = (T * 128 + wn * 64 + j * 16 + lrow) & 255;
                    O[(size_t)row * CD + c] = __float2bfloat16(acc[i][j][r]);
                }
            }
        }
    }
}

// ---------------------------------------------------------------------------
// Kernel 2: local attention. 512 threads = 8 waves = 8 consecutive positions.
// All operands bf16: Q from QA (in-place output), K/V from d_out scratch,
// pos_emb staged once per block into LDS as bf16 (49*128 uints = 25 KB).
// Lane -> channels 4*lane..+3 (head = lane>>3); 8-lane shfl_xor reduce.
// ---------------------------------------------------------------------------
__global__ __launch_bounds__(512) void attn_kernel(
    unsigned int* QA,                         // bf16x2 [NPOS][128], in+out
    const unsigned int* __restrict__ Kd,      // bf16x2 [NPOS][128]
    const unsigned int* __restrict__ Vd,      // bf16x2 [NPOS][128]
    const float* __restrict__ pe)             // f32 [49][256]
{
    __shared__ unsigned int pes[49 * 128];
    const int t = threadIdx.x;
    for (int idx = t; idx < 49 * 128; idx += 512) {
        float2 p = ((const float2*)pe)[idx];
        pes[idx] = packbf2(p.x, p.y);
    }
    __syncthreads();

    const int lane = t & 63;
    const int pos = blockIdx.x * 8 + (t >> 6);
    const int xx = pos & 63;
    const int yy = (pos >> 6) & 63;
    const int bb = pos >> 12;
    const int cy = min(max(yy, 3), 60);
    const int cx = min(max(xx, 3), 60);
    const int c2 = lane * 2;                  // packed-uint channel index

    unsigned int* qp = QA + (size_t)pos * 128 + c2;
    const unsigned int q01 = qp[0], q23 = qp[1];
    const float qx = bflo(q01), qy = bfhi(q01), qz = bflo(q23), qw = bfhi(q23);

    float m = -1e9f, l = 0.f;
    float a0 = 0.f, a1 = 0.f, a2 = 0.f, a3 = 0.f;
    const int center = (bb << 12) + (cy << 6) + cx;

    for (int sy = 0; sy < 7; ++sy) {
        const int nbase = center + ((sy - 3) << 6) - 3;
#pragma unroll
        for (int sx = 0; sx < 7; ++sx) {
            const int np = nbase + sx;
            const int s  = sy * 7 + sx;
            const uint2 kk = *(const uint2*)(Kd + (size_t)np * 128 + c2);
            const uint2 pp = *(const uint2*)(pes + s * 128 + c2);
            float k0 = bflo(kk.x) + bflo(pp.x);
            float k1 = bfhi(kk.x) + bfhi(pp.x);
            float k2 = bflo(kk.y) + bflo(pp.y);
            float k3 = bfhi(kk.y) + bfhi(pp.y);
            float part = fmaf(qx, k0, fmaf(qy, k1, fmaf(qz, k2, qw * k3)));
            part += __shfl_xor(part, 1);
            part += __shfl_xor(part, 2);
            part += __shfl_xor(part, 4);
            float sc = part * 0.17677669529663687f;   // 1/sqrt(32)
            float nm = fmaxf(m, sc);
            float alpha = __expf(m - nm);
            float p = __expf(sc - nm);
            l = l * alpha + p;
            const uint2 vv = *(const uint2*)(Vd + (size_t)np * 128 + c2);
            a0 = fmaf(a0, alpha, p * bflo(vv.x));
            a1 = fmaf(a1, alpha, p * bfhi(vv.x));
            a2 = fmaf(a2, alpha, p * bflo(vv.y));
            a3 = fmaf(a3, alpha, p * bfhi(vv.y));
            m = nm;
        }
    }
    const float inv = 1.f / (l + 1e-8f);
    qp[0] = packbf2(a0 * inv, a1 * inv);
    qp[1] = packbf2(a2 * inv, a3 * inv);
}

// ---------------------------------------------------------------------------
// Kernel 3: output projection via MFMA. out[16384x256] = A(bf16) @ Wo.
// grid = (128, 2). A staged to LDS by straight uint4 copy (already bf16).
// Overwrites d_out (K/V scratch is dead after attn; stream-ordered).
// ---------------------------------------------------------------------------
__global__ __launch_bounds__(256) void oproj_mfma(
    const unsigned int* __restrict__ A,       // QA as uint [NPOS][128]
    const __hip_bfloat16* __restrict__ Wofrag,
    float* __restrict__ out)
{
    __shared__ __align__(16) short As[128 * 32];
    const int t = threadIdx.x;
    const int rowbase = blockIdx.x * 128;
    const int T = blockIdx.y;
    const int L = t & 63;
    const int wave = t >> 6;
    const int wm = wave & 1, wn = wave >> 1;
    const int quad = L >> 4, lrow = L & 15;

    f32x4 zero = {0.f, 0.f, 0.f, 0.f};
    f32x4 acc[4][4];
#pragma unroll
    for (int i = 0; i < 4; ++i)
#pragma unroll
        for (int j = 0; j < 4; ++j) acc[i][j] = zero;

    const int r_st = t >> 1;
    const uint4* asrc = (const uint4*)A + (size_t)(rowbase + r_st) * 32 + (t & 1) * 2;
    uint4* As4 = (uint4*)As;
    const int as4_idx = r_st * 4 + (t & 1) * 2;

    for (int s = 0; s < 8; ++s) {
        if (s) __syncthreads();
        uint4 g0 = asrc[s * 4];
        uint4 g1 = asrc[s * 4 + 1];
        As4[as4_idx] = g0; As4[as4_idx + 1] = g1;
        __syncthreads();

        bf16x8 bf[4];
#pragma unroll
        for (int j = 0; j < 4; ++j)
            bf[j] = *(const bf16x8*)(Wofrag +
                     ((size_t)((T * 8 + s) * 8 + wn * 4 + j) * 64 + L) * 8);
#pragma unroll
        for (int i = 0; i < 4; ++i) {
            bf16x8 af = *(const bf16x8*)(As + (wm * 64 + i * 16 + lrow) * 32 + quad * 8);
#pragma unroll
            for (int j = 0; j < 4; ++j)
                acc[i][j] = __builtin_amdgcn_mfma_f32_16x16x32_bf16(af, bf[j], acc[i][j], 0, 0, 0);
        }
    }

#pragma unroll
    for (int i = 0; i < 4; ++i)
#pragma unroll
        for (int r = 0; r < 4; ++r) {
            int row = rowbase + wm * 64 + i * 16 + quad * 4 + r;
#pragma unroll
            for (int j = 0; j < 4; ++j) {
                int c = T * 128 + wn * 64 + j * 16 + lrow;
                out[(size_t)row * CD + c] = acc[i][j][r];
            }
        }
}

// ---------------------------------------------------------------------------
// Memory plan:
//   ws[0, 8MB):            QA bf16 (Q w/ pos_emb -> in-place attn output A)
//   ws[8MB, +384KB):       Wfrag   (QKV weights, b-frag order, bf16)
//   ws[+384KB, +128KB):    Wofrag  (Wo, b-frag order, bf16)     total 8.5 MB
//   d_out[0,8MB) / [8,16MB): K / V bf16 scratch; oproj overwrites with f32 out
// ---------------------------------------------------------------------------
extern "C" void kernel_launch(void* const* d_in, const int* in_sizes, int n_in,
                              void* d_out, int out_size, void* d_ws, size_t ws_size,
                              hipStream_t stream)
{
    const float* x  = (const float*)d_in[0];
    const float* Wq = (const float*)d_in[1];
    const float* Wk = (const float*)d_in[2];
    const float* Wv = (const float*)d_in[3];
    const float* Wo = (const float*)d_in[4];
    const float* pe = (const float*)d_in[5];
    float* out = (float*)d_out;

    char* ws = (char*)d_ws;
    __hip_bfloat16* QA     = (__hip_bfloat16*)ws;
    __hip_bfloat16* Wfrag  = (__hip_bfloat16*)(ws + (8u << 20));
    __hip_bfloat16* Wofrag = (__hip_bfloat16*)(ws + (8u << 20) + (384u << 10));
    __hip_bfloat16* Kd = (__hip_bfloat16*)d_out;
    __hip_bfloat16* Vd = (__hip_bfloat16*)((char*)d_out + (8u << 20));

    convert_kernel<<<128, 256, 0, stream>>>(Wq, Wk, Wv, Wo, Wfrag, Wofrag);
    qkv_mfma<<<dim3(128, 6), 256, 0, stream>>>(x, Wfrag, pe, QA, Kd, Vd);
    attn_kernel<<<2048, 512, 0, stream>>>((unsigned int*)QA,
                                          (const unsigned int*)Kd,
                                          (const unsigned int*)Vd, pe);
    oproj_mfma<<<dim3(128, 2), 256, 0, stream>>>((const unsigned int*)QA, Wofrag, out);
}